// Round 2
// baseline (503.622 us; speedup 1.0000x reference)
//
#include <hip/hip_runtime.h>
#include <hip/hip_bf16.h>

typedef __hip_bfloat16 bf16;
typedef __attribute__((ext_vector_type(8))) short short8;
typedef __attribute__((ext_vector_type(4))) float float4v;

#define Hd 256
#define Wd 256
#define HW 65536
#define CO 64

// ---------------------------------------------------------------------------
// K1: style MLP + modulated/demodulated conv weights (fp32 in, bf16 out),
// swizzled for MFMA A-frags.
// wA layout: [s][kc(18)][o(64)][32]  where k = tap*64 + i, kc = k>>5
// ---------------------------------------------------------------------------
__global__ __launch_bounds__(64) void k1_style(
    const float* __restrict__ vec, const float* __restrict__ w1,
    const float* __restrict__ w2, const float* __restrict__ wconv,
    bf16* __restrict__ wA)
{
    int s = blockIdx.x;
    int lane = threadIdx.x;
    __shared__ float svec[256];
    __shared__ float sm[64];
    for (int i = lane; i < 256; i += 64) svec[i] = vec[s * 256 + i];
    __syncthreads();

    float hid[16];
#pragma unroll
    for (int j = 0; j < 16; ++j) {
        float p = 0.f;
#pragma unroll
        for (int q = 0; q < 4; ++q) {
            int c = lane + q * 64;
            p += svec[c] * w1[j * 256 + c];
        }
#pragma unroll
        for (int off = 32; off >= 1; off >>= 1) p += __shfl_xor(p, off, 64);
        hid[j] = p > 0.f ? p : 0.1f * p;   // LeakyReLU(0.1)
    }
    float sty = 0.f;
#pragma unroll
    for (int j = 0; j < 16; ++j) sty += w2[lane * 16 + j] * hid[j];
    sm[lane] = sty + 1.0f;
    __syncthreads();

    int o = lane;
    float sumsq = 0.f;
    for (int i = 0; i < 64; ++i) {
        float mi = sm[i];
#pragma unroll
        for (int t = 0; t < 9; ++t) {
            float wv = wconv[(o * 64 + i) * 9 + t] * mi;
            sumsq += wv * wv;
        }
    }
    float d = rsqrtf(sumsq + 1e-8f);
    bf16* wAs = wA + s * (18 * 64 * 32);
    for (int i = 0; i < 64; ++i) {
        float mi = sm[i] * d;
#pragma unroll
        for (int t = 0; t < 9; ++t) {
            float v = wconv[(o * 64 + i) * 9 + t] * mi;
            int k = t * 64 + i;                       // K order: tap-major
            wAs[(k >> 5) * 2048 + o * 32 + (k & 31)] = (bf16)v;
        }
    }
}

// ---------------------------------------------------------------------------
// K2: ChanNorm (fp32 in, bf16 out). One block per (s, h, 128-px strip).
// Output layout channel-chunked: nxT[s][h][c8(8)][w(256)][cj(8)] bf16
// -> all global I/O coalesced.
// ---------------------------------------------------------------------------
__global__ __launch_bounds__(128) void k2_norm(
    const float* __restrict__ x, const float* __restrict__ g,
    const float* __restrict__ bb, bf16* __restrict__ nxT)
{
    int bx = blockIdx.x;           // 0..511
    int h  = bx >> 1;
    int w0 = (bx & 1) * 128;
    int s  = blockIdx.y;
    int t  = threadIdx.x;          // 0..127
    __shared__ __align__(16) float xrow[64 * 128];   // [c][w], 32 KB
    __shared__ float sg[64], sb[64];
    if (t < 64) { sg[t] = g[t]; sb[t] = bb[t]; }

    const float* xs = x + (size_t)s * CO * HW + h * Wd + w0;
#pragma unroll
    for (int it = 0; it < 16; ++it) {
        int id = it * 128 + t;          // 0..2047 uint4 chunks (4 floats each)
        int c = id >> 5, q = id & 31;   // c: 0..63, q: 0..31 (q*4 = px)
        *(float4*)&xrow[c * 128 + q * 4] = *(const float4*)&xs[(size_t)c * HW + q * 4];
    }
    __syncthreads();

    int w = t;                          // local px 0..127
    float s1 = 0.f, s2 = 0.f;
#pragma unroll
    for (int c = 0; c < 64; ++c) {
        float f = xrow[c * 128 + w];
        s1 += f; s2 += f * f;
    }
    float mean = s1 * (1.f / 64);
    float var  = s2 * (1.f / 64) - mean * mean;
    float rstd = rsqrtf(var + 1e-5f);

    bf16* dst = nxT + (size_t)(s * Hd + h) * (8 * Wd * 8);
#pragma unroll
    for (int c8 = 0; c8 < 8; ++c8) {
        bf16 ov[8];
#pragma unroll
        for (int k = 0; k < 8; ++k) {
            int c = c8 * 8 + k;
            float f = xrow[c * 128 + w];
            ov[k] = (bf16)((f - mean) * rstd * sg[c] + sb[c]);
        }
        *(uint4*)&dst[(c8 * Wd + w0 + w) * 8] = *(uint4*)ov;
    }
}

// ---------------------------------------------------------------------------
// K3: implicit-GEMM 3x3 conv + residual (bf16 MFMA, fp32 residual/out).
// Block: one (s, h, 128-px strip). C[64 o x 128 px] = W[64 x 576] * P[576 x 128]
// K = tap*64 + i (tap-major). LDS tile: [3 rows][130 px][8 chunks of 8ch],
// chunk XOR-swizzled by (wl&7).
// ---------------------------------------------------------------------------
#define NT 128
__global__ __launch_bounds__(256) void k3_conv(
    const bf16* __restrict__ nxT, const bf16* __restrict__ wA,
    const float* __restrict__ x, float* __restrict__ out)
{
    int wt = blockIdx.x;   // 0..1
    int h  = blockIdx.y;   // 0..255
    int s  = blockIdx.z;   // 0..7
    int t  = threadIdx.x;
    int w0 = wt * NT;
    __shared__ __align__(16) bf16 tile[3 * 130 * 64];   // 49,920 B

    // stage 3 halo rows, 130 px, 64 ch (as 8 chunks of 8), zero-pad borders
    for (int id = t; id < 3 * 130 * 8; id += 256) {
        int c8 = id & 7;
        int wl = (id >> 3) % 130;
        int dh = (id >> 3) / 130;
        int row  = h + dh - 1;
        int wabs = w0 + wl - 1;
        uint4 v = make_uint4(0u, 0u, 0u, 0u);
        if (row >= 0 && row < Hd && wabs >= 0 && wabs < Wd)
            v = *(const uint4*)&nxT[(((size_t)(s * Hd + row) * 8 + c8) * Wd + wabs) * 8];
        *(uint4*)&tile[((dh * 130 + wl) * 8 + (c8 ^ (wl & 7))) * 8] = v;
    }
    __syncthreads();

    int wv   = t >> 6;     // wave 0..3 -> pixel strip [wv*32, wv*32+32)
    int lane = t & 63;
    int col  = lane & 15;
    int quad = lane >> 4;

    float4v acc[4][2];
#pragma unroll
    for (int mt = 0; mt < 4; ++mt)
#pragma unroll
        for (int nt = 0; nt < 2; ++nt) acc[mt][nt] = (float4v)0.f;

    const bf16* wAs = wA + s * (18 * 64 * 32);
#pragma unroll
    for (int kc = 0; kc < 18; ++kc) {
        int tap = kc >> 1;
        int kh = tap / 3, kw = tap % 3;
        int ch8 = (kc & 1) * 4 + quad;          // channel chunk this lane needs
        short8 bfr[2];
#pragma unroll
        for (int nt = 0; nt < 2; ++nt) {
            int wl = wv * 32 + nt * 16 + col + kw;   // B[k][n]: n = lane&15
            union { uint4 u; short8 s8; } u;
            u.u = *(const uint4*)&tile[((kh * 130 + wl) * 8 + (ch8 ^ (wl & 7))) * 8];
            bfr[nt] = u.s8;
        }
#pragma unroll
        for (int mt = 0; mt < 4; ++mt) {
            union { uint4 u; short8 s8; } a;     // A[m][k]: m = lane&15
            a.u = *(const uint4*)&wAs[kc * 2048 + (mt * 16 + col) * 32 + quad * 8];
#pragma unroll
            for (int nt = 0; nt < 2; ++nt)
                acc[mt][nt] = __builtin_amdgcn_mfma_f32_16x16x32_bf16(
                    a.s8, bfr[nt], acc[mt][nt], 0, 0, 0);
        }
    }

    // epilogue: C/D layout col = lane&15 (pixel), row = quad*4 + r (o); + residual
#pragma unroll
    for (int mt = 0; mt < 4; ++mt) {
#pragma unroll
        for (int nt = 0; nt < 2; ++nt) {
#pragma unroll
            for (int r = 0; r < 4; ++r) {
                int o = mt * 16 + quad * 4 + r;
                int w = w0 + wv * 32 + nt * 16 + col;
                size_t idx = (size_t)(s * CO + o) * HW + h * Wd + w;
                out[idx] = acc[mt][nt][r] + x[idx];
            }
        }
    }
}

extern "C" void kernel_launch(void* const* d_in, const int* in_sizes, int n_in,
                              void* d_out, int out_size, void* d_ws, size_t ws_size,
                              hipStream_t stream)
{
    const float* x     = (const float*)d_in[0];
    const float* vec   = (const float*)d_in[1];
    const float* g     = (const float*)d_in[2];
    const float* bb    = (const float*)d_in[3];
    const float* w1    = (const float*)d_in[4];
    const float* w2    = (const float*)d_in[5];
    const float* wconv = (const float*)d_in[6];
    float* out = (float*)d_out;

    // ws layout: wA (8*18*64*32 bf16 = 576 KB) at 0, nxT (67 MB bf16) at 1 MB
    bf16* wA  = (bf16*)d_ws;
    bf16* nxT = (bf16*)((char*)d_ws + (1u << 20));

    k1_style<<<8, 64, 0, stream>>>(vec, w1, w2, wconv, wA);
    k2_norm<<<dim3(512, 8), 128, 0, stream>>>(x, g, bb, nxT);
    k3_conv<<<dim3(2, Hd, 8), 256, 0, stream>>>(nxT, wA, x, out);
}

// Round 3
// 382.327 us; speedup vs baseline: 1.3173x; 1.3173x over previous
//
#include <hip/hip_runtime.h>
#include <hip/hip_bf16.h>

typedef __hip_bfloat16 bf16;
typedef __attribute__((ext_vector_type(8))) short short8;
typedef __attribute__((ext_vector_type(4))) float float4v;

#define Hd 256
#define Wd 256
#define HW 65536
#define CO 64

// ---------------------------------------------------------------------------
// K1: style MLP + modulated/demodulated weights. One block per (o, s).
// wA layout: [s][kc(18)][o(64)][32], k = tap*64 + i (tap-major).
// ---------------------------------------------------------------------------
__global__ __launch_bounds__(64) void k1_style(
    const float* __restrict__ vec, const float* __restrict__ w1,
    const float* __restrict__ w2, const float* __restrict__ wconv,
    bf16* __restrict__ wA)
{
    int o = blockIdx.x;      // 0..63
    int s = blockIdx.y;      // 0..7
    int i = threadIdx.x;     // lane = input channel

    float sv[4];
#pragma unroll
    for (int q = 0; q < 4; ++q) sv[q] = vec[s * 256 + q * 64 + i];

    float hid[16];
#pragma unroll
    for (int j = 0; j < 16; ++j) {
        float p = 0.f;
#pragma unroll
        for (int q = 0; q < 4; ++q) p += sv[q] * w1[j * 256 + q * 64 + i];
#pragma unroll
        for (int off = 32; off >= 1; off >>= 1) p += __shfl_xor(p, off, 64);
        hid[j] = p > 0.f ? p : 0.1f * p;   // LeakyReLU(0.1)
    }
    float sty = 0.f;
#pragma unroll
    for (int j = 0; j < 16; ++j) sty += w2[i * 16 + j] * hid[j];
    float msty = sty + 1.0f;               // per input-channel i

    float wrow[9];
#pragma unroll
    for (int tt = 0; tt < 9; ++tt) wrow[tt] = wconv[(o * 64 + i) * 9 + tt] * msty;
    float ss = 0.f;
#pragma unroll
    for (int tt = 0; tt < 9; ++tt) ss += wrow[tt] * wrow[tt];
#pragma unroll
    for (int off = 32; off >= 1; off >>= 1) ss += __shfl_xor(ss, off, 64);
    float d = rsqrtf(ss + 1e-8f);

    bf16* wAs = wA + s * (18 * 64 * 32);
#pragma unroll
    for (int tt = 0; tt < 9; ++tt) {
        int k = tt * 64 + i;
        wAs[(k >> 5) * 2048 + o * 32 + (k & 31)] = (bf16)(wrow[tt] * d);
    }
}

// ---------------------------------------------------------------------------
// K2: ChanNorm, no LDS for data: 1 thread = 1 pixel, 64 ch in VGPRs.
// Output nxT[s][h][c8(8)][w(256)][8] bf16, fully coalesced uint4 stores.
// ---------------------------------------------------------------------------
__global__ __launch_bounds__(256) void k2_norm(
    const float* __restrict__ x, const float* __restrict__ gg,
    const float* __restrict__ bb, bf16* __restrict__ nxT)
{
    __shared__ float sg[64], sb[64];
    int t = threadIdx.x;
    if (t < 64) { sg[t] = gg[t]; sb[t] = bb[t]; }
    __syncthreads();

    int s  = blockIdx.y;
    int px = blockIdx.x * 256 + t;
    int h  = px >> 8, w = px & 255;

    const float* xs = x + (size_t)s * (CO * HW) + px;
    float v[64];
    float s1 = 0.f, s2 = 0.f;
#pragma unroll
    for (int c = 0; c < 64; ++c) {
        float f = xs[(size_t)c * HW];
        v[c] = f; s1 += f; s2 += f * f;
    }
    float mean = s1 * (1.f / 64);
    float var  = s2 * (1.f / 64) - mean * mean;
    float rstd = rsqrtf(var + 1e-5f);

    bf16* dst = nxT + ((size_t)(s * Hd + h) * 8 * Wd + w) * 8;
#pragma unroll
    for (int c8 = 0; c8 < 8; ++c8) {
        bf16 ov[8];
#pragma unroll
        for (int k = 0; k < 8; ++k) {
            int c = c8 * 8 + k;
            ov[k] = (bf16)((v[c] - mean) * rstd * sg[c] + sb[c]);
        }
        *(uint4*)&dst[(size_t)c8 * (Wd * 8)] = *(uint4*)ov;
    }
}

// ---------------------------------------------------------------------------
// K3: implicit-GEMM 3x3 conv + residual. Block = (s, 8 rows, 64 px).
// A-frags preloaded to VGPRs (reused 8 rows). Rolling 4-slot LDS row window,
// software-pipelined: load row r+2 -> regs, compute row r, write regs -> LDS.
// Slot layout [c8(8)][wl(68 pad, 66 used)][8] bf16.
// ---------------------------------------------------------------------------
#define SLOT_ELEMS (8 * 68 * 8)   // 4352 elems = 8704 B; 4 slots = 34816 B
__global__ __launch_bounds__(256, 4) void k3_conv(
    const bf16* __restrict__ nxT, const bf16* __restrict__ wA,
    const float* __restrict__ x, float* __restrict__ out)
{
    int w0 = blockIdx.x * 64;     // 0..3
    int h0 = blockIdx.y * 8;      // 0..31
    int s  = blockIdx.z;
    int t  = threadIdx.x;
    __shared__ __align__(16) bf16 tile[4 * SLOT_ELEMS];

    int wave = t >> 6;            // = o-group 0..3
    int lane = t & 63;
    int col  = lane & 15;
    int quad = lane >> 4;

    // preload A fragments: 18 kc for this wave's 16 o-rows
    const bf16* wAs = wA + s * (18 * 64 * 32);
    short8 afrag[18];
#pragma unroll
    for (int kc = 0; kc < 18; ++kc) {
        union { uint4 u; short8 s8; } a;
        a.u = *(const uint4*)&wAs[kc * 2048 + (wave * 16 + col) * 32 + quad * 8];
        afrag[kc] = a.s8;
    }

    // full (load+write) staging of one global row g into its slot
    auto stage_row_now = [&](int g) {
        bf16* dst = tile + ((g + 4) & 3) * SLOT_ELEMS;
        const bf16* src = nxT + (size_t)(s * Hd + g) * (8 * Wd * 8);
        bool gok = (g >= 0 && g < Hd);
#pragma unroll
        for (int j = 0; j < 3; ++j) {
            int idx = j * 256 + t;
            if (idx < 528) {
                int c8 = idx / 66;
                int wl = idx - c8 * 66;
                int wabs = w0 + wl - 1;
                uint4 v = make_uint4(0u, 0u, 0u, 0u);
                if (gok && wabs >= 0 && wabs < Wd)
                    v = *(const uint4*)&src[(c8 * Wd + wabs) * 8];
                *(uint4*)&dst[(c8 * 68 + wl) * 8] = v;
            }
        }
    };

    stage_row_now(h0 - 1);
    stage_row_now(h0);
    stage_row_now(h0 + 1);
    __syncthreads();

#pragma unroll 1
    for (int r = 0; r < 8; ++r) {
        int grow = h0 + r;

        // ---- staging load phase (row grow+2) : issue global loads only ----
        uint4 stg[3];
        int   soff[3];
        bool  sdo[3];
        int g2 = grow + 2;
        bool do_stage = (r < 7);
        bool gok = do_stage && (g2 >= 0 && g2 < Hd);
        const bf16* src = nxT + (size_t)(s * Hd + g2) * (8 * Wd * 8);
#pragma unroll
        for (int j = 0; j < 3; ++j) {
            int idx = j * 256 + t;
            sdo[j] = do_stage && (idx < 528);
            int c8 = idx / 66;
            int wl = idx - c8 * 66;
            int wabs = w0 + wl - 1;
            soff[j] = (c8 * 68 + wl) * 8;
            stg[j] = make_uint4(0u, 0u, 0u, 0u);
            if (sdo[j] && gok && wabs >= 0 && wabs < Wd)
                stg[j] = *(const uint4*)&src[(c8 * Wd + wabs) * 8];
        }

        // ---- compute row grow (pure LDS + MFMA) ----
        float4v acc[4];
#pragma unroll
        for (int nt = 0; nt < 4; ++nt) acc[nt] = (float4v)0.f;

#pragma unroll
        for (int kc = 0; kc < 18; ++kc) {
            int tap = kc >> 1;
            int kh = tap / 3, kw = tap - kh * 3;
            int ch8 = (kc & 1) * 4 + quad;
            const bf16* slotp = tile + ((grow - 1 + kh + 4) & 3) * SLOT_ELEMS;
#pragma unroll
            for (int nt = 0; nt < 4; ++nt) {
                int wl = nt * 16 + col + kw;
                union { uint4 u; short8 s8; } b;
                b.u = *(const uint4*)&slotp[(ch8 * 68 + wl) * 8];
                acc[nt] = __builtin_amdgcn_mfma_f32_16x16x32_bf16(
                    afrag[kc], b.s8, acc[nt], 0, 0, 0);
            }
        }

        // ---- staging write phase (loads have drained behind 72 MFMAs) ----
        bf16* sdst = tile + ((g2 + 4) & 3) * SLOT_ELEMS;
#pragma unroll
        for (int j = 0; j < 3; ++j)
            if (sdo[j]) *(uint4*)&sdst[soff[j]] = stg[j];

        // ---- epilogue: residual + store (C/D: col=pixel, row=o) ----
#pragma unroll
        for (int nt = 0; nt < 4; ++nt) {
#pragma unroll
            for (int rr = 0; rr < 4; ++rr) {
                int o = wave * 16 + quad * 4 + rr;
                int w = w0 + nt * 16 + col;
                size_t idx = (size_t)(s * CO + o) * HW + grow * Wd + w;
                out[idx] = acc[nt][rr] + x[idx];
            }
        }
        __syncthreads();
    }
}

extern "C" void kernel_launch(void* const* d_in, const int* in_sizes, int n_in,
                              void* d_out, int out_size, void* d_ws, size_t ws_size,
                              hipStream_t stream)
{
    const float* x     = (const float*)d_in[0];
    const float* vec   = (const float*)d_in[1];
    const float* g     = (const float*)d_in[2];
    const float* bb    = (const float*)d_in[3];
    const float* w1    = (const float*)d_in[4];
    const float* w2    = (const float*)d_in[5];
    const float* wconv = (const float*)d_in[6];
    float* out = (float*)d_out;

    bf16* wA  = (bf16*)d_ws;                         // 576 KB
    bf16* nxT = (bf16*)((char*)d_ws + (1u << 20));   // 67 MB

    k1_style<<<dim3(64, 8), 64, 0, stream>>>(vec, w1, w2, wconv, wA);
    k2_norm<<<dim3(256, 8), 256, 0, stream>>>(x, g, bb, nxT);
    k3_conv<<<dim3(4, 32, 8), 256, 0, stream>>>(nxT, wA, x, out);
}

// Round 4
// 315.041 us; speedup vs baseline: 1.5986x; 1.2136x over previous
//
#include <hip/hip_runtime.h>
#include <hip/hip_bf16.h>

typedef __hip_bfloat16 bf16;
typedef __attribute__((ext_vector_type(8))) short short8;
typedef __attribute__((ext_vector_type(4))) float float4v;

#define Hd 256
#define Wd 256
#define HW 65536
#define CO 64

// ---------------------------------------------------------------------------
// K1: style MLP + modulated/demodulated weights. One block per (o, s).
// wA layout: [s][kc(18)][o(64)][32], k = tap*64 + i (tap-major).
// ---------------------------------------------------------------------------
__global__ __launch_bounds__(64) void k1_style(
    const float* __restrict__ vec, const float* __restrict__ w1,
    const float* __restrict__ w2, const float* __restrict__ wconv,
    bf16* __restrict__ wA)
{
    int o = blockIdx.x;      // 0..63
    int s = blockIdx.y;      // 0..7
    int i = threadIdx.x;     // lane = input channel

    float sv[4];
#pragma unroll
    for (int q = 0; q < 4; ++q) sv[q] = vec[s * 256 + q * 64 + i];

    float hid[16];
#pragma unroll
    for (int j = 0; j < 16; ++j) {
        float p = 0.f;
#pragma unroll
        for (int q = 0; q < 4; ++q) p += sv[q] * w1[j * 256 + q * 64 + i];
#pragma unroll
        for (int off = 32; off >= 1; off >>= 1) p += __shfl_xor(p, off, 64);
        hid[j] = p > 0.f ? p : 0.1f * p;   // LeakyReLU(0.1)
    }
    float sty = 0.f;
#pragma unroll
    for (int j = 0; j < 16; ++j) sty += w2[i * 16 + j] * hid[j];
    float msty = sty + 1.0f;               // per input-channel i

    float wrow[9];
#pragma unroll
    for (int tt = 0; tt < 9; ++tt) wrow[tt] = wconv[(o * 64 + i) * 9 + tt] * msty;
    float ss = 0.f;
#pragma unroll
    for (int tt = 0; tt < 9; ++tt) ss += wrow[tt] * wrow[tt];
#pragma unroll
    for (int off = 32; off >= 1; off >>= 1) ss += __shfl_xor(ss, off, 64);
    float d = rsqrtf(ss + 1e-8f);

    bf16* wAs = wA + s * (18 * 64 * 32);
#pragma unroll
    for (int tt = 0; tt < 9; ++tt) {
        int k = tt * 64 + i;
        wAs[(k >> 5) * 2048 + o * 32 + (k & 31)] = (bf16)(wrow[tt] * d);
    }
}

// ---------------------------------------------------------------------------
// K3: FUSED ChanNorm + implicit-GEMM 3x3 conv + residual.
// Block = (s, 8 output rows, 32-px strip). Stage 10 halo rows x 34 px:
// per-thread per-pixel channel-norm (fp32 x -> bf16), ONE barrier, then
// 8 rows of barrier-free ds_read+MFMA+epilogue.
// Tile layout: [row(10)][c8(8)][wl(34)][8] bf16; ch8 stride 544B == 32 mod 128.
// Waves 2x2: wave = 32 o (2 mt, A-frags resident in VGPRs) x 16 px.
// ---------------------------------------------------------------------------
#define PXB 32
#define ROWS 8
#define TR 10
#define WL 34
#define ROW_ELEMS (8 * WL * 8)   // 2176 elems = 4352 B; 10 rows = 43520 B

__global__ __launch_bounds__(256, 2) void k3_fused(
    const float* __restrict__ x, const float* __restrict__ gg,
    const float* __restrict__ bb, const bf16* __restrict__ wA,
    float* __restrict__ out)
{
    int w0 = blockIdx.x * PXB;   // 0..7 -> 0..224
    int h0 = blockIdx.y * ROWS;  // 0..31 -> 0..248
    int s  = blockIdx.z;
    int t  = threadIdx.x;
    __shared__ __align__(16) bf16 tile[TR * ROW_ELEMS];
    __shared__ float sg[64], sb[64];
    if (t < 64) { sg[t] = gg[t]; sb[t] = bb[t]; }
    __syncthreads();

    // ---- stage + fused ChanNorm: 340 (row,px) sites, thread-per-pixel ----
    for (int p = t; p < TR * WL; p += 256) {
        int dr = p / WL, wl = p - dr * WL;
        int grow = h0 + dr - 1, wabs = w0 + wl - 1;
        bf16* dst = &tile[dr * ROW_ELEMS + wl * 8];
        if (grow >= 0 && grow < Hd && wabs >= 0 && wabs < Wd) {
            const float* xp = x + (size_t)s * (CO * HW) + (size_t)grow * Wd + wabs;
            float v[64], s1 = 0.f, s2 = 0.f;
#pragma unroll
            for (int c = 0; c < 64; ++c) {
                float f = xp[(size_t)c * HW];
                v[c] = f; s1 += f; s2 += f * f;
            }
            float mean = s1 * (1.f / 64);
            float var  = s2 * (1.f / 64) - mean * mean;
            float rstd = rsqrtf(var + 1e-5f);
#pragma unroll
            for (int c8 = 0; c8 < 8; ++c8) {
                bf16 ov[8];
#pragma unroll
                for (int k = 0; k < 8; ++k) {
                    int c = c8 * 8 + k;
                    ov[k] = (bf16)((v[c] - mean) * rstd * sg[c] + sb[c]);
                }
                *(uint4*)&dst[c8 * (WL * 8)] = *(uint4*)ov;
            }
        } else {
            uint4 z = make_uint4(0u, 0u, 0u, 0u);
#pragma unroll
            for (int c8 = 0; c8 < 8; ++c8) *(uint4*)&dst[c8 * (WL * 8)] = z;
        }
    }
    __syncthreads();   // the ONLY compute barrier

    int wave = t >> 6, lane = t & 63;
    int mi = wave & 1, ni = wave >> 1;   // wave tile: o in [mi*32,+32), px in [ni*16,+16)
    int col = lane & 15, quad = lane >> 4;

    // preload A fragments: 18 kc x 2 mt, resident across all 8 rows
    const bf16* wAs = wA + s * (18 * 64 * 32);
    short8 afrag[18][2];
#pragma unroll
    for (int kc = 0; kc < 18; ++kc)
#pragma unroll
        for (int mt = 0; mt < 2; ++mt) {
            union { uint4 u; short8 s8; } a;
            a.u = *(const uint4*)&wAs[kc * 2048 + (mi * 32 + mt * 16 + col) * 32 + quad * 8];
            afrag[kc][mt] = a.s8;
        }

#pragma unroll 2
    for (int r = 0; r < ROWS; ++r) {
        float4v acc[2];
        acc[0] = (float4v)0.f; acc[1] = (float4v)0.f;
#pragma unroll
        for (int kc = 0; kc < 18; ++kc) {
            int tap = kc >> 1;
            int kh = tap / 3, kw = tap - kh * 3;
            int ch8 = (kc & 1) * 4 + quad;
            int wl = ni * 16 + col + kw;          // <= 33
            union { uint4 u; short8 s8; } b;
            b.u = *(const uint4*)&tile[(r + kh) * ROW_ELEMS + (ch8 * WL + wl) * 8];
            acc[0] = __builtin_amdgcn_mfma_f32_16x16x32_bf16(afrag[kc][0], b.s8, acc[0], 0, 0, 0);
            acc[1] = __builtin_amdgcn_mfma_f32_16x16x32_bf16(afrag[kc][1], b.s8, acc[1], 0, 0, 0);
        }
        // epilogue: residual (L2-hot, same block staged these bytes) + store
        int grow = h0 + r;
        int wpx  = w0 + ni * 16 + col;
#pragma unroll
        for (int mt = 0; mt < 2; ++mt) {
#pragma unroll
            for (int rr = 0; rr < 4; ++rr) {
                int o = mi * 32 + mt * 16 + quad * 4 + rr;
                size_t idx = (size_t)(s * CO + o) * HW + (size_t)grow * Wd + wpx;
                out[idx] = acc[mt][rr] + x[idx];
            }
        }
    }
}

extern "C" void kernel_launch(void* const* d_in, const int* in_sizes, int n_in,
                              void* d_out, int out_size, void* d_ws, size_t ws_size,
                              hipStream_t stream)
{
    const float* x     = (const float*)d_in[0];
    const float* vec   = (const float*)d_in[1];
    const float* g     = (const float*)d_in[2];
    const float* bb    = (const float*)d_in[3];
    const float* w1    = (const float*)d_in[4];
    const float* w2    = (const float*)d_in[5];
    const float* wconv = (const float*)d_in[6];
    float* out = (float*)d_out;

    bf16* wA = (bf16*)d_ws;    // 8*18*64*32 bf16 = 576 KB

    k1_style<<<dim3(64, 8), 64, 0, stream>>>(vec, w1, w2, wconv, wA);
    k3_fused<<<dim3(8, 32, 8), 256, 0, stream>>>(x, g, bb, wA, out);
}